// Round 15
// baseline (530.718 us; speedup 1.0000x reference)
//
#include <hip/hip_runtime.h>
#include <hip/hip_bf16.h>
#include <math.h>

#define N_NODES 10000
#define N_EDGES 320000
#define HID 64
#define N_LAYERS 4
#define EDGE_BLOCKS 625
#define EDGE_WAVES 8              /* 512-thread blocks; 625*8*4*16 = 320000 exact */
#define EDGE_TILES_PER_WAVE 4
#define N_TILES_NODE 625
#define ALD 72                    /* act LDS leading dim (ushort): 2-way = free */

typedef unsigned short ushort_t;
typedef unsigned int uint_t;
typedef __attribute__((ext_vector_type(8))) short short8;
typedef __attribute__((ext_vector_type(4))) float floatx4;

__device__ __forceinline__ float silu_f(float x) {
    return x * (1.0f / (1.0f + __expf(-x)));
}
__device__ __forceinline__ ushort_t f2bf(float f) {
    uint_t u = __float_as_uint(f);
    uint_t r = u + 0x7FFFu + ((u >> 16) & 1u);   // RNE
    return (ushort_t)(r >> 16);
}
__device__ __forceinline__ float bf2f(ushort_t u) {
    return __uint_as_float(((uint_t)u) << 16);
}
__device__ __forceinline__ uint_t pk2bf(float a, float b) {
    __hip_bfloat162 t = __float22bfloat162_rn(float2{a, b});
    union { __hip_bfloat162 h; uint_t u; } cv; cv.h = t; return cv.u;
}

// ---------------- embedding + state init (merged) ----------------
__global__ __launch_bounds__(64) void embed_kernel(const float* __restrict__ his,
                                                   const float* __restrict__ loc,
                                                   const float* __restrict__ vel,
                                                   const float* __restrict__ w,
                                                   const float* __restrict__ b,
                                                   float* __restrict__ h0,
                                                   ushort_t* __restrict__ hbf,
                                                   float* __restrict__ x, float* __restrict__ v,
                                                   float* __restrict__ iv) {
    int i = blockIdx.x, l = threadIdx.x;
    float acc = b[l];
    #pragma unroll
    for (int k = 0; k < 4; ++k) acc += his[i*4+k] * w[k*HID+l];
    h0[i*HID+l] = acc;
    hbf[i*HID+l] = f2bf(acc);
    if (l == 0) {
        float v0 = vel[3*i], v1 = vel[3*i+1], v2 = vel[3*i+2];
        float nrm = sqrtf(v0*v0 + v1*v1 + v2*v2) + 1e-8f;
        x[3*i] = loc[3*i]; x[3*i+1] = loc[3*i+1]; x[3*i+2] = loc[3*i+2];
        v[3*i] = v0; v[3*i+1] = v1; v[3*i+2] = v2;
        iv[3*i] = v0/nrm; iv[3*i+1] = v1/nrm; iv[3*i+2] = v2/nrm;
    }
}

// ---------------- CSR build ----------------
__global__ void count_kernel(const int* __restrict__ erow, int* __restrict__ counts) {
    int e = blockIdx.x * blockDim.x + threadIdx.x;
    if (e < N_EDGES) atomicAdd(&counts[erow[e]], 1);
}

__global__ __launch_bounds__(256) void scan_kernel(const int* __restrict__ counts,
                                                   int* __restrict__ offs) {
    __shared__ int part[256];
    const int t = threadIdx.x;
    const int base = t * 40;
    int s0 = 0;
    for (int k = 0; k < 40; ++k) {
        int i = base + k;
        if (i < N_NODES) s0 += counts[i];
    }
    part[t] = s0;
    __syncthreads();
    for (int d = 1; d < 256; d <<= 1) {
        int vv = (t >= d) ? part[t-d] : 0;
        __syncthreads();
        part[t] += vv;
        __syncthreads();
    }
    int run = part[t] - s0;
    for (int k = 0; k < 40; ++k) {
        int i = base + k;
        if (i < N_NODES) { run += counts[i]; offs[i+1] = run; }
    }
    if (t == 0) offs[0] = 0;
}

__global__ void scatter_kernel(const int* __restrict__ erow, const int* __restrict__ ecol,
                               const float* __restrict__ eattr,
                               const int* __restrict__ offs,
                               int* __restrict__ cursor,
                               int* __restrict__ srow, int* __restrict__ scol,
                               float* __restrict__ seattr) {
    int e = blockIdx.x * blockDim.x + threadIdx.x;
    if (e < N_EDGES) {
        int r = erow[e];
        int p = atomicAdd(&cursor[r], 1);
        int pos = offs[r] + p;
        srow[pos] = r;
        scol[pos] = ecol[e];
        seattr[2*pos]   = eattr[2*e];
        seattr[2*pos+1] = eattr[2*e+1];
    }
}

// ---------------- weight pack ----------------
__device__ __forceinline__ void pack_one(const float* __restrict__ src, ushort_t* __restrict__ dst,
                                         int u) {
    int kt = u >> 8, nt = (u >> 6) & 3, lane = u & 63;
    int quad = lane >> 4, lo = lane & 15;
    #pragma unroll
    for (int j = 0; j < 8; ++j) {
        int k = 32*kt + quad*8 + j, n = 16*nt + lo;
        dst[(size_t)u*8 + j] = f2bf(src[k*HID + n]);
    }
}
__global__ void pack_weights(const float* __restrict__ ew1, const float* __restrict__ ew2,
                             const float* __restrict__ cw1, const float* __restrict__ nw1,
                             const float* __restrict__ nw2, const float* __restrict__ vw1,
                             ushort_t* __restrict__ pw1, ushort_t* __restrict__ pw2,
                             ushort_t* __restrict__ pc1, ushort_t* __restrict__ pn1,
                             ushort_t* __restrict__ pn2, ushort_t* __restrict__ pv1) {
    int t = blockIdx.x * blockDim.x + threadIdx.x;
    if      (t < 1024) pack_one(ew1, pw1, t);
    else if (t < 1536) pack_one(ew2, pw2, t - 1024);
    else if (t < 2048) pack_one(cw1, pc1, t - 1536);
    else if (t < 3072) pack_one(nw1, pn1, t - 2048);
    else if (t < 3584) pack_one(nw2, pn2, t - 3072);
    else               pack_one(vw1, pv1, t - 3584);
}

// ---------------- MFMA edge kernel: 8 waves/block, all blocks co-resident, 1 barrier/tile ----------------
__global__ __launch_bounds__(512, 6) void edge_kernel(
    const ushort_t* __restrict__ hbf, const float* __restrict__ x,
    const int* __restrict__ srow, const int* __restrict__ scol,
    const float* __restrict__ seattr,
    const float* __restrict__ ew1,   // ragged rows 128..130 (f32)
    const float* __restrict__ eb1, const float* __restrict__ eb2,
    const float* __restrict__ cb1, const float* __restrict__ cw2,
    const ushort_t* __restrict__ pw1, const ushort_t* __restrict__ pw2,
    const ushort_t* __restrict__ pc1,
    float* __restrict__ aggf, float* __restrict__ accf)
{
    __shared__ ushort_t sW1[4*4*64*8];   // 16 KB
    __shared__ ushort_t sW2[2*4*64*8];   // 8 KB
    __shared__ float sRW[3][HID];
    __shared__ float sB1[HID], sB2[HID], sCB1[HID], sCW2[HID];
    __shared__ ushort_t sAct[EDGE_WAVES][16*ALD]; // wave-private
    __shared__ float sEdge[EDGE_WAVES][16][8];    // wave-private

    const int wave = threadIdx.x >> 6, lane = threadIdx.x & 63;
    const int quad = lane >> 4, lo = lane & 15;

    // CW1 B-fragments in registers (32 VGPR — proven no-spill at VGPR 60)
    short8 c1f[8];
    #pragma unroll
    for (int u = 0; u < 8; ++u)
        c1f[u] = *(const short8*)(pc1 + ((size_t)u*64 + lane)*8);

    for (int i = threadIdx.x; i < 4*4*64*8; i += 512) sW1[i] = pw1[i];
    for (int i = threadIdx.x; i < 2*4*64*8; i += 512) sW2[i] = pw2[i];
    for (int i = threadIdx.x; i < 3*HID; i += 512) sRW[i/HID][i%HID] = ew1[(128 + i/HID)*HID + (i%HID)];
    if (threadIdx.x < HID) {
        sB1[threadIdx.x]  = eb1[threadIdx.x];
        sB2[threadIdx.x]  = eb2[threadIdx.x];
        sCB1[threadIdx.x] = cb1[threadIdx.x];
        sCW2[threadIdx.x] = cw2[threadIdx.x];
    }
    __syncthreads();

    ushort_t* act = sAct[wave];
    float (*sed)[8] = sEdge[wave];

    int tile = blockIdx.x * EDGE_WAVES + wave;
    for (int it = 0; it < EDGE_TILES_PER_WAVE; ++it, tile += EDGE_BLOCKS*EDGE_WAVES) {
        const int p0 = tile * 16;
        const int rme = srow[p0 + lo], cme = scol[p0 + lo];
        if (lane < 16) {
            float d0 = x[3*rme]   - x[3*cme];
            float d1 = x[3*rme+1] - x[3*cme+1];
            float d2 = x[3*rme+2] - x[3*cme+2];
            const float2 ea = ((const float2*)seattr)[p0 + lane];
            sed[lane][0] = d0; sed[lane][1] = d1; sed[lane][2] = d2;
            sed[lane][3] = d0*d0 + d1*d1 + d2*d2;
            sed[lane][4] = ea.x; sed[lane][5] = ea.y;
        }
        const int nxt = __shfl(rme, (lane + 1) & 63, 64);
        unsigned long long bm = __ballot((lane < 16) && ((lane == 15) || (rme != nxt)));
        const uint_t bnd = (uint_t)(bm & 0xFFFFu);

        const ushort_t* hr = hbf + (size_t)rme * HID;
        const ushort_t* hc = hbf + (size_t)cme * HID;
        short8 af0 = *(const short8*)(hr + quad*8);
        short8 af1 = *(const short8*)(hr + 32 + quad*8);
        short8 af2 = *(const short8*)(hc + quad*8);
        short8 af3 = *(const short8*)(hc + 32 + quad*8);

        // ---- GEMM1: [16x128] @ W1[128x64]
        floatx4 acc[4];
        #pragma unroll
        for (int nt = 0; nt < 4; ++nt) {
            floatx4 a = {0.f, 0.f, 0.f, 0.f};
            a = __builtin_amdgcn_mfma_f32_16x16x32_bf16(af0, *(const short8*)(sW1 + ((0*4+nt)*64+lane)*8), a, 0, 0, 0);
            a = __builtin_amdgcn_mfma_f32_16x16x32_bf16(af1, *(const short8*)(sW1 + ((1*4+nt)*64+lane)*8), a, 0, 0, 0);
            a = __builtin_amdgcn_mfma_f32_16x16x32_bf16(af2, *(const short8*)(sW1 + ((2*4+nt)*64+lane)*8), a, 0, 0, 0);
            a = __builtin_amdgcn_mfma_f32_16x16x32_bf16(af3, *(const short8*)(sW1 + ((3*4+nt)*64+lane)*8), a, 0, 0, 0);
            acc[nt] = a;
        }
        float rad[4], ea0[4], ea1[4];
        #pragma unroll
        for (int r = 0; r < 4; ++r) {
            const int m = 4*quad + r;
            rad[r] = sed[m][3]; ea0[r] = sed[m][4]; ea1[r] = sed[m][5];
        }
        #pragma unroll
        for (int nt = 0; nt < 4; ++nt) {
            const int n = 16*nt + lo;
            const float w128 = sRW[0][n], w129 = sRW[1][n], w130 = sRW[2][n], b1 = sB1[n];
            float vv[4];
            #pragma unroll
            for (int r = 0; r < 4; ++r)
                vv[r] = silu_f(acc[nt][r] + rad[r]*w128 + ea0[r]*w129 + ea1[r]*w130 + b1);
            const uint_t p01 = pk2bf(vv[0], vv[1]);
            const uint_t p23 = pk2bf(vv[2], vv[3]);
            act[(4*quad + 0)*ALD + n] = (ushort_t)(p01 & 0xFFFFu);
            act[(4*quad + 1)*ALD + n] = (ushort_t)(p01 >> 16);
            act[(4*quad + 2)*ALD + n] = (ushort_t)(p23 & 0xFFFFu);
            act[(4*quad + 3)*ALD + n] = (ushort_t)(p23 >> 16);
        }

        // ---- GEMM2: f1[16x64] @ W2[64x64]
        short8 g0 = *(const short8*)(act + lo*ALD + quad*8);
        short8 g1 = *(const short8*)(act + lo*ALD + 32 + quad*8);
        floatx4 acc2[4];
        #pragma unroll
        for (int nt = 0; nt < 4; ++nt) {
            floatx4 a = {0.f, 0.f, 0.f, 0.f};
            a = __builtin_amdgcn_mfma_f32_16x16x32_bf16(g0, *(const short8*)(sW2 + ((0*4+nt)*64+lane)*8), a, 0, 0, 0);
            a = __builtin_amdgcn_mfma_f32_16x16x32_bf16(g1, *(const short8*)(sW2 + ((1*4+nt)*64+lane)*8), a, 0, 0, 0);
            acc2[nt] = a;
        }
        #pragma unroll
        for (int nt = 0; nt < 4; ++nt) {
            const int n = 16*nt + lo;
            const float b2 = sB2[n];
            float vv[4];
            #pragma unroll
            for (int r = 0; r < 4; ++r) vv[r] = silu_f(acc2[nt][r] + b2);
            const uint_t p01 = pk2bf(vv[0], vv[1]);
            const uint_t p23 = pk2bf(vv[2], vv[3]);
            act[(4*quad + 0)*ALD + n] = (ushort_t)(p01 & 0xFFFFu);
            act[(4*quad + 1)*ALD + n] = (ushort_t)(p01 >> 16);
            act[(4*quad + 2)*ALD + n] = (ushort_t)(p23 & 0xFFFFu);
            act[(4*quad + 3)*ALD + n] = (ushort_t)(p23 >> 16);
        }

        // ---- fused segment-sum of ef (per-lane channel c = lane)
        {
            float s = 0.f;
            #pragma unroll
            for (int m = 0; m < 16; ++m) {
                s += bf2f(act[m*ALD + lane]);
                if ((bnd >> m) & 1u) {
                    const int row = __shfl(rme, m, 64);
                    atomicAdd(&aggf[(size_t)row*HID + lane], s);
                    s = 0.f;
                }
            }
        }

        // ---- GEMM3: ef @ CW1 -> silu -> dot cw2 -> gate
        short8 q0 = *(const short8*)(act + lo*ALD + quad*8);
        short8 q1 = *(const short8*)(act + lo*ALD + 32 + quad*8);
        float gs[4] = {0.f, 0.f, 0.f, 0.f};
        #pragma unroll
        for (int nt = 0; nt < 4; ++nt) {
            floatx4 a = {0.f, 0.f, 0.f, 0.f};
            a = __builtin_amdgcn_mfma_f32_16x16x32_bf16(q0, c1f[0*4+nt], a, 0, 0, 0);
            a = __builtin_amdgcn_mfma_f32_16x16x32_bf16(q1, c1f[1*4+nt], a, 0, 0, 0);
            const int n = 16*nt + lo;
            const float cb = sCB1[n], cw = sCW2[n];
            #pragma unroll
            for (int r = 0; r < 4; ++r) gs[r] += silu_f(a[r] + cb) * cw;
        }
        #pragma unroll
        for (int off = 1; off < 16; off <<= 1) {
            #pragma unroll
            for (int r = 0; r < 4; ++r) gs[r] += __shfl_xor(gs[r], off, 64);
        }
        int rr[4];
        #pragma unroll
        for (int r = 0; r < 4; ++r) rr[r] = __shfl(rme, 4*quad + r, 64);
        if (lo < 3) {
            #pragma unroll
            for (int r = 0; r < 4; ++r) {
                const int m = 4*quad + r;
                atomicAdd(&accf[(size_t)rr[r]*3 + lo], sed[m][lo] * gs[r]);
            }
        }
        __syncthreads();   // single per-tile lockstep barrier (L2 locality)
    }
}

// ---------------- MFMA node kernel: one 16-node tile per 64-thread block ----------------
__global__ __launch_bounds__(64) void node_kernel(
    const float* __restrict__ h_in, float* __restrict__ h_out, ushort_t* __restrict__ hbf,
    float* __restrict__ x, float* __restrict__ v, const float* __restrict__ iv,
    float* __restrict__ aggf, float* __restrict__ accf,
    const int* __restrict__ offs,
    const ushort_t* __restrict__ pn1, const ushort_t* __restrict__ pn2,
    const ushort_t* __restrict__ pv1,
    const float* __restrict__ nb1, const float* __restrict__ nb2,
    const float* __restrict__ vb1, const float* __restrict__ vb2,
    const float* __restrict__ vw2,
    float* __restrict__ outx, float* __restrict__ outv)
{
    __shared__ ushort_t t1[16*ALD];
    __shared__ float sPhi[16];

    const int lane = threadIdx.x;
    const int tile = blockIdx.x;
    const int quad = lane >> 4, lo = lane & 15;
    const int i0 = tile * 16;

    int ov = 0;
    if (lane < 17) ov = offs[i0 + lane];

    const ushort_t* hrow = hbf + (size_t)(i0 + lo) * HID;
    short8 af0 = *(const short8*)(hrow + quad*8);
    short8 af1 = *(const short8*)(hrow + 32 + quad*8);
    float* ag = aggf + (size_t)(i0 + lo) * HID + quad*8;
    short8 af2, af3;
    #pragma unroll
    for (int j = 0; j < 4; ++j) {
        const uint_t u2 = pk2bf(ag[2*j], ag[2*j+1]);
        const uint_t u3 = pk2bf(ag[32 + 2*j], ag[32 + 2*j+1]);
        af2[2*j] = (short)(u2 & 0xFFFFu); af2[2*j+1] = (short)(u2 >> 16);
        af3[2*j] = (short)(u3 & 0xFFFFu); af3[2*j+1] = (short)(u3 >> 16);
    }
    floatx4 z = {0.f, 0.f, 0.f, 0.f};
    *(floatx4*)(ag)      = z;
    *(floatx4*)(ag + 4)  = z;
    *(floatx4*)(ag + 32) = z;
    *(floatx4*)(ag + 36) = z;

    #pragma unroll
    for (int nt = 0; nt < 4; ++nt) {
        floatx4 a = {0.f, 0.f, 0.f, 0.f};
        a = __builtin_amdgcn_mfma_f32_16x16x32_bf16(af0, *(const short8*)(pn1 + ((size_t)(0*4+nt)*64+lane)*8), a, 0, 0, 0);
        a = __builtin_amdgcn_mfma_f32_16x16x32_bf16(af1, *(const short8*)(pn1 + ((size_t)(1*4+nt)*64+lane)*8), a, 0, 0, 0);
        a = __builtin_amdgcn_mfma_f32_16x16x32_bf16(af2, *(const short8*)(pn1 + ((size_t)(2*4+nt)*64+lane)*8), a, 0, 0, 0);
        a = __builtin_amdgcn_mfma_f32_16x16x32_bf16(af3, *(const short8*)(pn1 + ((size_t)(3*4+nt)*64+lane)*8), a, 0, 0, 0);
        const int n = 16*nt + lo;
        const float b1 = nb1[n];
        float vv[4];
        #pragma unroll
        for (int r = 0; r < 4; ++r) vv[r] = silu_f(a[r] + b1);
        const uint_t p01 = pk2bf(vv[0], vv[1]);
        const uint_t p23 = pk2bf(vv[2], vv[3]);
        t1[(4*quad + 0)*ALD + n] = (ushort_t)(p01 & 0xFFFFu);
        t1[(4*quad + 1)*ALD + n] = (ushort_t)(p01 >> 16);
        t1[(4*quad + 2)*ALD + n] = (ushort_t)(p23 & 0xFFFFu);
        t1[(4*quad + 3)*ALD + n] = (ushort_t)(p23 >> 16);
    }

    short8 g0 = *(const short8*)(t1 + lo*ALD + quad*8);
    short8 g1 = *(const short8*)(t1 + lo*ALD + 32 + quad*8);
    #pragma unroll
    for (int nt = 0; nt < 4; ++nt) {
        floatx4 a = {0.f, 0.f, 0.f, 0.f};
        a = __builtin_amdgcn_mfma_f32_16x16x32_bf16(g0, *(const short8*)(pn2 + ((size_t)(0*4+nt)*64+lane)*8), a, 0, 0, 0);
        a = __builtin_amdgcn_mfma_f32_16x16x32_bf16(g1, *(const short8*)(pn2 + ((size_t)(1*4+nt)*64+lane)*8), a, 0, 0, 0);
        const int n = 16*nt + lo;
        const float b2 = nb2[n];
        #pragma unroll
        for (int r = 0; r < 4; ++r) {
            const int i = i0 + 4*quad + r;
            const float hnew = h_in[(size_t)i*HID + n] + a[r] + b2;
            h_out[(size_t)i*HID + n] = hnew;
            hbf[(size_t)i*HID + n] = f2bf(hnew);
        }
    }

    float gs[4] = {0.f, 0.f, 0.f, 0.f};
    #pragma unroll
    for (int nt = 0; nt < 4; ++nt) {
        floatx4 a = {0.f, 0.f, 0.f, 0.f};
        a = __builtin_amdgcn_mfma_f32_16x16x32_bf16(af0, *(const short8*)(pv1 + ((size_t)(0*4+nt)*64+lane)*8), a, 0, 0, 0);
        a = __builtin_amdgcn_mfma_f32_16x16x32_bf16(af1, *(const short8*)(pv1 + ((size_t)(1*4+nt)*64+lane)*8), a, 0, 0, 0);
        const int n = 16*nt + lo;
        const float b1 = vb1[n], w2 = vw2[n];
        #pragma unroll
        for (int r = 0; r < 4; ++r) gs[r] += silu_f(a[r] + b1) * w2;
    }
    #pragma unroll
    for (int off = 1; off < 16; off <<= 1) {
        #pragma unroll
        for (int r = 0; r < 4; ++r) gs[r] += __shfl_xor(gs[r], off, 64);
    }
    const float vb2s = vb2[0];
    if (lo == 0) {
        #pragma unroll
        for (int r = 0; r < 4; ++r) sPhi[4*quad + r] = gs[r] + vb2s;
    }

    if (lane < 48) {
        const int m = lane / 3, d = lane - m*3;
        const int s = __shfl(ov, m, 64), t = __shfl(ov, m + 1, 64);
        const int cnt = t - s;
        const int i = i0 + m;
        const float accm = accf[(size_t)i*3 + d] / (float)(cnt > 0 ? cnt : 1);
        accf[(size_t)i*3 + d] = 0.f;
        const float phi = sPhi[m];
        const float vn = v[3*i + d] + accm + phi * iv[3*i + d];
        const float xn = x[3*i + d] + vn;
        v[3*i + d] = vn;
        x[3*i + d] = xn;
        if (outx) {
            outx[3*i + d] = xn;
            outv[3*i + d] = vn;
        }
    }
}

extern "C" void kernel_launch(void* const* d_in, const int* in_sizes, int n_in,
                              void* d_out, int out_size, void* d_ws, size_t ws_size,
                              hipStream_t stream) {
    const float* his   = (const float*)d_in[0];
    const float* loc   = (const float*)d_in[1];
    const int*   edges = (const int*)  d_in[2];
    const float* vel   = (const float*)d_in[3];
    const float* eattr = (const float*)d_in[4];
    const float* emb_w = (const float*)d_in[5];
    const float* emb_b = (const float*)d_in[6];
    const float* ew1 = (const float*)d_in[7];
    const float* eb1 = (const float*)d_in[8];
    const float* ew2 = (const float*)d_in[9];
    const float* eb2 = (const float*)d_in[10];
    const float* nw1 = (const float*)d_in[11];
    const float* nb1 = (const float*)d_in[12];
    const float* nw2 = (const float*)d_in[13];
    const float* nb2 = (const float*)d_in[14];
    const float* cw1 = (const float*)d_in[15];
    const float* cb1 = (const float*)d_in[16];
    const float* cw2 = (const float*)d_in[17];
    const float* vw1 = (const float*)d_in[18];
    const float* vb1 = (const float*)d_in[19];
    const float* vw2 = (const float*)d_in[20];
    const float* vb2 = (const float*)d_in[21];

    const int* erow = edges;
    const int* ecol = edges + N_EDGES;

    char* ws = (char*)d_ws;
    size_t off = 0;
    auto walloc = [&](size_t bytes) -> void* {
        void* p = ws + off; off += (bytes + 255) & ~(size_t)255; return p;
    };
    float* h_a      = (float*)walloc((size_t)N_NODES*HID*4);
    float* h_b      = (float*)walloc((size_t)N_NODES*HID*4);
    ushort_t* hbf   = (ushort_t*)walloc((size_t)N_NODES*HID*2);
    float* xb       = (float*)walloc((size_t)N_NODES*3*4);
    float* vb       = (float*)walloc((size_t)N_NODES*3*4);
    float* ivb      = (float*)walloc((size_t)N_NODES*3*4);
    float* aggf     = (float*)walloc((size_t)N_NODES*HID*4);
    float* accf     = (float*)walloc((size_t)N_NODES*3*4);
    int* counts     = (int*)walloc((size_t)N_NODES*4);
    int* cursor     = (int*)walloc((size_t)N_NODES*4);
    int* offs       = (int*)walloc((size_t)(N_NODES+1)*4);
    int* srow       = (int*)walloc((size_t)N_EDGES*4);
    int* scol       = (int*)walloc((size_t)N_EDGES*4);
    float* seattr   = (float*)walloc((size_t)N_EDGES*2*4);
    ushort_t* pw1   = (ushort_t*)walloc((size_t)4*4*64*8*2);
    ushort_t* pw2   = (ushort_t*)walloc((size_t)2*4*64*8*2);
    ushort_t* pc1   = (ushort_t*)walloc((size_t)2*4*64*8*2);
    ushort_t* pn1   = (ushort_t*)walloc((size_t)4*4*64*8*2);
    ushort_t* pn2   = (ushort_t*)walloc((size_t)2*4*64*8*2);
    ushort_t* pv1   = (ushort_t*)walloc((size_t)2*4*64*8*2);

    float* out = (float*)d_out;
    const int nx = 3*N_NODES, nh = HID*N_NODES;

    (void)hipMemsetAsync(counts, 0, (size_t)N_NODES*4, stream);
    (void)hipMemsetAsync(cursor, 0, (size_t)N_NODES*4, stream);
    (void)hipMemsetAsync(aggf, 0, (size_t)N_NODES*HID*4, stream);
    (void)hipMemsetAsync(accf, 0, (size_t)N_NODES*3*4, stream);

    embed_kernel<<<N_NODES, 64, 0, stream>>>(his, loc, vel, emb_w, emb_b, h_a, hbf,
                                             xb, vb, ivb);
    count_kernel<<<(N_EDGES+255)/256, 256, 0, stream>>>(erow, counts);
    scan_kernel<<<1, 256, 0, stream>>>(counts, offs);
    scatter_kernel<<<(N_EDGES+255)/256, 256, 0, stream>>>(erow, ecol, eattr, offs, cursor,
                                                          srow, scol, seattr);
    pack_weights<<<16, 256, 0, stream>>>(ew1, ew2, cw1, nw1, nw2, vw1,
                                         pw1, pw2, pc1, pn1, pn2, pv1);

    float* h_cur = h_a;
    float* h_nxt = h_b;
    for (int layer = 0; layer < N_LAYERS; ++layer) {
        const bool last = (layer == N_LAYERS - 1);
        edge_kernel<<<EDGE_BLOCKS, 512, 0, stream>>>(hbf, xb, srow, scol, seattr,
                                                     ew1, eb1, eb2, cb1, cw2,
                                                     pw1, pw2, pc1, aggf, accf);
        node_kernel<<<N_TILES_NODE, 64, 0, stream>>>(h_cur,
                                                     last ? (out + nx) : h_nxt,
                                                     hbf, xb, vb, ivb,
                                                     aggf, accf, offs,
                                                     pn1, pn2, pv1,
                                                     nb1, nb2, vb1, vb2, vw2,
                                                     last ? out : nullptr,
                                                     last ? (out + nx + nh) : nullptr);
        float* tmp = h_cur; h_cur = h_nxt; h_nxt = tmp;
    }
}

// Round 16
// 467.462 us; speedup vs baseline: 1.1353x; 1.1353x over previous
//
#include <hip/hip_runtime.h>
#include <hip/hip_bf16.h>
#include <math.h>

#define N_NODES 10000
#define N_EDGES 320000
#define HID 64
#define N_LAYERS 4
#define EDGE_BLOCKS 1024          /* all co-resident: 4 blocks/CU * 256 CU */
#define EDGE_TILES_PER_WAVE 5     /* 1024*4*5 = 20480 slots >= 20000 tiles (guarded) */
#define N_TILES_EDGE 20000
#define N_TILES_NODE 625
#define ALD 72                    /* act LDS leading dim (ushort): 2-way = free */

typedef unsigned short ushort_t;
typedef unsigned int uint_t;
typedef __attribute__((ext_vector_type(8))) short short8;
typedef __attribute__((ext_vector_type(4))) float floatx4;

__device__ __forceinline__ float silu_f(float x) {
    return x * (1.0f / (1.0f + __expf(-x)));
}
__device__ __forceinline__ ushort_t f2bf(float f) {
    uint_t u = __float_as_uint(f);
    uint_t r = u + 0x7FFFu + ((u >> 16) & 1u);   // RNE
    return (ushort_t)(r >> 16);
}
__device__ __forceinline__ float bf2f(ushort_t u) {
    return __uint_as_float(((uint_t)u) << 16);
}
__device__ __forceinline__ uint_t pk2bf(float a, float b) {
    __hip_bfloat162 t = __float22bfloat162_rn(float2{a, b});
    union { __hip_bfloat162 h; uint_t u; } cv; cv.h = t; return cv.u;
}

// ---------------- embedding + state init (merged) ----------------
__global__ __launch_bounds__(64) void embed_kernel(const float* __restrict__ his,
                                                   const float* __restrict__ loc,
                                                   const float* __restrict__ vel,
                                                   const float* __restrict__ w,
                                                   const float* __restrict__ b,
                                                   float* __restrict__ h0,
                                                   ushort_t* __restrict__ hbf,
                                                   float* __restrict__ x, float* __restrict__ v,
                                                   float* __restrict__ iv) {
    int i = blockIdx.x, l = threadIdx.x;
    float acc = b[l];
    #pragma unroll
    for (int k = 0; k < 4; ++k) acc += his[i*4+k] * w[k*HID+l];
    h0[i*HID+l] = acc;
    hbf[i*HID+l] = f2bf(acc);
    if (l == 0) {
        float v0 = vel[3*i], v1 = vel[3*i+1], v2 = vel[3*i+2];
        float nrm = sqrtf(v0*v0 + v1*v1 + v2*v2) + 1e-8f;
        x[3*i] = loc[3*i]; x[3*i+1] = loc[3*i+1]; x[3*i+2] = loc[3*i+2];
        v[3*i] = v0; v[3*i+1] = v1; v[3*i+2] = v2;
        iv[3*i] = v0/nrm; iv[3*i+1] = v1/nrm; iv[3*i+2] = v2/nrm;
    }
}

// ---------------- CSR build ----------------
__global__ void count_kernel(const int* __restrict__ erow, int* __restrict__ counts) {
    int e = blockIdx.x * blockDim.x + threadIdx.x;
    if (e < N_EDGES) atomicAdd(&counts[erow[e]], 1);
}

__global__ __launch_bounds__(256) void scan_kernel(const int* __restrict__ counts,
                                                   int* __restrict__ offs) {
    __shared__ int part[256];
    const int t = threadIdx.x;
    const int base = t * 40;
    int s0 = 0;
    for (int k = 0; k < 40; ++k) {
        int i = base + k;
        if (i < N_NODES) s0 += counts[i];
    }
    part[t] = s0;
    __syncthreads();
    for (int d = 1; d < 256; d <<= 1) {
        int vv = (t >= d) ? part[t-d] : 0;
        __syncthreads();
        part[t] += vv;
        __syncthreads();
    }
    int run = part[t] - s0;
    for (int k = 0; k < 40; ++k) {
        int i = base + k;
        if (i < N_NODES) { run += counts[i]; offs[i+1] = run; }
    }
    if (t == 0) offs[0] = 0;
}

__global__ void scatter_kernel(const int* __restrict__ erow, const int* __restrict__ ecol,
                               const float* __restrict__ eattr,
                               const int* __restrict__ offs,
                               int* __restrict__ cursor,
                               int* __restrict__ srow, int* __restrict__ scol,
                               float* __restrict__ seattr) {
    int e = blockIdx.x * blockDim.x + threadIdx.x;
    if (e < N_EDGES) {
        int r = erow[e];
        int p = atomicAdd(&cursor[r], 1);
        int pos = offs[r] + p;
        srow[pos] = r;
        scol[pos] = ecol[e];
        seattr[2*pos]   = eattr[2*e];
        seattr[2*pos+1] = eattr[2*e+1];
    }
}

// ---------------- weight pack ----------------
__device__ __forceinline__ void pack_one(const float* __restrict__ src, ushort_t* __restrict__ dst,
                                         int u) {
    int kt = u >> 8, nt = (u >> 6) & 3, lane = u & 63;
    int quad = lane >> 4, lo = lane & 15;
    #pragma unroll
    for (int j = 0; j < 8; ++j) {
        int k = 32*kt + quad*8 + j, n = 16*nt + lo;
        dst[(size_t)u*8 + j] = f2bf(src[k*HID + n]);
    }
}
__global__ void pack_weights(const float* __restrict__ ew1, const float* __restrict__ ew2,
                             const float* __restrict__ cw1, const float* __restrict__ nw1,
                             const float* __restrict__ nw2, const float* __restrict__ vw1,
                             ushort_t* __restrict__ pw1, ushort_t* __restrict__ pw2,
                             ushort_t* __restrict__ pc1, ushort_t* __restrict__ pn1,
                             ushort_t* __restrict__ pn2, ushort_t* __restrict__ pv1) {
    int t = blockIdx.x * blockDim.x + threadIdx.x;
    if      (t < 1024) pack_one(ew1, pw1, t);
    else if (t < 1536) pack_one(ew2, pw2, t - 1024);
    else if (t < 2048) pack_one(cw1, pc1, t - 1536);
    else if (t < 3072) pack_one(nw1, pn1, t - 2048);
    else if (t < 3584) pack_one(nw2, pn2, t - 3072);
    else               pack_one(vw1, pv1, t - 3584);
}

// ---------------- MFMA edge kernel (R14 body): 1 barrier/tile; CW1 in regs; zero-tail grid ----------------
__global__ __launch_bounds__(256, 4) void edge_kernel(
    const ushort_t* __restrict__ hbf, const float* __restrict__ x,
    const int* __restrict__ srow, const int* __restrict__ scol,
    const float* __restrict__ seattr,
    const float* __restrict__ ew1,   // ragged rows 128..130 (f32)
    const float* __restrict__ eb1, const float* __restrict__ eb2,
    const float* __restrict__ cb1, const float* __restrict__ cw2,
    const ushort_t* __restrict__ pw1, const ushort_t* __restrict__ pw2,
    const ushort_t* __restrict__ pc1,
    float* __restrict__ aggf, float* __restrict__ accf)
{
    __shared__ ushort_t sW1[4*4*64*8];   // 16 KB
    __shared__ ushort_t sW2[2*4*64*8];   // 8 KB
    __shared__ float sRW[3][HID];
    __shared__ float sB1[HID], sB2[HID], sCB1[HID], sCW2[HID];
    __shared__ ushort_t sAct[4][16*ALD]; // wave-private
    __shared__ float sEdge[4][16][8];    // wave-private

    const int wave = threadIdx.x >> 6, lane = threadIdx.x & 63;
    const int quad = lane >> 4, lo = lane & 15;

    // CW1 B-fragments in registers (32 VGPR — no spill at VGPR 60; W2 stays in LDS)
    short8 c1f[8];
    #pragma unroll
    for (int u = 0; u < 8; ++u)
        c1f[u] = *(const short8*)(pc1 + ((size_t)u*64 + lane)*8);

    for (int i = threadIdx.x; i < 4*4*64*8; i += 256) sW1[i] = pw1[i];
    for (int i = threadIdx.x; i < 2*4*64*8; i += 256) sW2[i] = pw2[i];
    for (int i = threadIdx.x; i < 3*HID; i += 256) sRW[i/HID][i%HID] = ew1[(128 + i/HID)*HID + (i%HID)];
    if (threadIdx.x < HID) {
        sB1[threadIdx.x]  = eb1[threadIdx.x];
        sB2[threadIdx.x]  = eb2[threadIdx.x];
        sCB1[threadIdx.x] = cb1[threadIdx.x];
        sCW2[threadIdx.x] = cw2[threadIdx.x];
    }
    __syncthreads();

    ushort_t* act = sAct[wave];
    float (*sed)[8] = sEdge[wave];

    int tile = blockIdx.x * 4 + wave;
    for (int it = 0; it < EDGE_TILES_PER_WAVE; ++it, tile += EDGE_BLOCKS*4) {
        if (tile < N_TILES_EDGE) {
            const int p0 = tile * 16;
            const int rme = srow[p0 + lo], cme = scol[p0 + lo];
            if (lane < 16) {
                float d0 = x[3*rme]   - x[3*cme];
                float d1 = x[3*rme+1] - x[3*cme+1];
                float d2 = x[3*rme+2] - x[3*cme+2];
                const float2 ea = ((const float2*)seattr)[p0 + lane];
                sed[lane][0] = d0; sed[lane][1] = d1; sed[lane][2] = d2;
                sed[lane][3] = d0*d0 + d1*d1 + d2*d2;
                sed[lane][4] = ea.x; sed[lane][5] = ea.y;
            }
            const int nxt = __shfl(rme, (lane + 1) & 63, 64);
            unsigned long long bm = __ballot((lane < 16) && ((lane == 15) || (rme != nxt)));
            const uint_t bnd = (uint_t)(bm & 0xFFFFu);

            const ushort_t* hr = hbf + (size_t)rme * HID;
            const ushort_t* hc = hbf + (size_t)cme * HID;
            short8 af0 = *(const short8*)(hr + quad*8);
            short8 af1 = *(const short8*)(hr + 32 + quad*8);
            short8 af2 = *(const short8*)(hc + quad*8);
            short8 af3 = *(const short8*)(hc + 32 + quad*8);

            // ---- GEMM1: [16x128] @ W1[128x64]
            floatx4 acc[4];
            #pragma unroll
            for (int nt = 0; nt < 4; ++nt) {
                floatx4 a = {0.f, 0.f, 0.f, 0.f};
                a = __builtin_amdgcn_mfma_f32_16x16x32_bf16(af0, *(const short8*)(sW1 + ((0*4+nt)*64+lane)*8), a, 0, 0, 0);
                a = __builtin_amdgcn_mfma_f32_16x16x32_bf16(af1, *(const short8*)(sW1 + ((1*4+nt)*64+lane)*8), a, 0, 0, 0);
                a = __builtin_amdgcn_mfma_f32_16x16x32_bf16(af2, *(const short8*)(sW1 + ((2*4+nt)*64+lane)*8), a, 0, 0, 0);
                a = __builtin_amdgcn_mfma_f32_16x16x32_bf16(af3, *(const short8*)(sW1 + ((3*4+nt)*64+lane)*8), a, 0, 0, 0);
                acc[nt] = a;
            }
            float rad[4], ea0[4], ea1[4];
            #pragma unroll
            for (int r = 0; r < 4; ++r) {
                const int m = 4*quad + r;
                rad[r] = sed[m][3]; ea0[r] = sed[m][4]; ea1[r] = sed[m][5];
            }
            #pragma unroll
            for (int nt = 0; nt < 4; ++nt) {
                const int n = 16*nt + lo;
                const float w128 = sRW[0][n], w129 = sRW[1][n], w130 = sRW[2][n], b1 = sB1[n];
                float vv[4];
                #pragma unroll
                for (int r = 0; r < 4; ++r)
                    vv[r] = silu_f(acc[nt][r] + rad[r]*w128 + ea0[r]*w129 + ea1[r]*w130 + b1);
                const uint_t p01 = pk2bf(vv[0], vv[1]);
                const uint_t p23 = pk2bf(vv[2], vv[3]);
                act[(4*quad + 0)*ALD + n] = (ushort_t)(p01 & 0xFFFFu);
                act[(4*quad + 1)*ALD + n] = (ushort_t)(p01 >> 16);
                act[(4*quad + 2)*ALD + n] = (ushort_t)(p23 & 0xFFFFu);
                act[(4*quad + 3)*ALD + n] = (ushort_t)(p23 >> 16);
            }

            // ---- GEMM2: f1[16x64] @ W2[64x64]
            short8 g0 = *(const short8*)(act + lo*ALD + quad*8);
            short8 g1 = *(const short8*)(act + lo*ALD + 32 + quad*8);
            floatx4 acc2[4];
            #pragma unroll
            for (int nt = 0; nt < 4; ++nt) {
                floatx4 a = {0.f, 0.f, 0.f, 0.f};
                a = __builtin_amdgcn_mfma_f32_16x16x32_bf16(g0, *(const short8*)(sW2 + ((0*4+nt)*64+lane)*8), a, 0, 0, 0);
                a = __builtin_amdgcn_mfma_f32_16x16x32_bf16(g1, *(const short8*)(sW2 + ((1*4+nt)*64+lane)*8), a, 0, 0, 0);
                acc2[nt] = a;
            }
            #pragma unroll
            for (int nt = 0; nt < 4; ++nt) {
                const int n = 16*nt + lo;
                const float b2 = sB2[n];
                float vv[4];
                #pragma unroll
                for (int r = 0; r < 4; ++r) vv[r] = silu_f(acc2[nt][r] + b2);
                const uint_t p01 = pk2bf(vv[0], vv[1]);
                const uint_t p23 = pk2bf(vv[2], vv[3]);
                act[(4*quad + 0)*ALD + n] = (ushort_t)(p01 & 0xFFFFu);
                act[(4*quad + 1)*ALD + n] = (ushort_t)(p01 >> 16);
                act[(4*quad + 2)*ALD + n] = (ushort_t)(p23 & 0xFFFFu);
                act[(4*quad + 3)*ALD + n] = (ushort_t)(p23 >> 16);
            }

            // ---- fused segment-sum of ef (per-lane channel c = lane)
            {
                float s = 0.f;
                #pragma unroll
                for (int m = 0; m < 16; ++m) {
                    s += bf2f(act[m*ALD + lane]);
                    if ((bnd >> m) & 1u) {
                        const int row = __shfl(rme, m, 64);
                        atomicAdd(&aggf[(size_t)row*HID + lane], s);
                        s = 0.f;
                    }
                }
            }

            // ---- GEMM3: ef @ CW1 -> silu -> dot cw2 -> gate
            short8 q0 = *(const short8*)(act + lo*ALD + quad*8);
            short8 q1 = *(const short8*)(act + lo*ALD + 32 + quad*8);
            float gs[4] = {0.f, 0.f, 0.f, 0.f};
            #pragma unroll
            for (int nt = 0; nt < 4; ++nt) {
                floatx4 a = {0.f, 0.f, 0.f, 0.f};
                a = __builtin_amdgcn_mfma_f32_16x16x32_bf16(q0, c1f[0*4+nt], a, 0, 0, 0);
                a = __builtin_amdgcn_mfma_f32_16x16x32_bf16(q1, c1f[1*4+nt], a, 0, 0, 0);
                const int n = 16*nt + lo;
                const float cb = sCB1[n], cw = sCW2[n];
                #pragma unroll
                for (int r = 0; r < 4; ++r) gs[r] += silu_f(a[r] + cb) * cw;
            }
            #pragma unroll
            for (int off = 1; off < 16; off <<= 1) {
                #pragma unroll
                for (int r = 0; r < 4; ++r) gs[r] += __shfl_xor(gs[r], off, 64);
            }
            int rr[4];
            #pragma unroll
            for (int r = 0; r < 4; ++r) rr[r] = __shfl(rme, 4*quad + r, 64);
            if (lo < 3) {
                #pragma unroll
                for (int r = 0; r < 4; ++r) {
                    const int m = 4*quad + r;
                    atomicAdd(&accf[(size_t)rr[r]*3 + lo], sed[m][lo] * gs[r]);
                }
            }
        }
        __syncthreads();   // single per-tile lockstep barrier (L2 locality; outside guard, tail-safe)
    }
}

// ---------------- MFMA node kernel: one 16-node tile per 64-thread block ----------------
__global__ __launch_bounds__(64) void node_kernel(
    const float* __restrict__ h_in, float* __restrict__ h_out, ushort_t* __restrict__ hbf,
    float* __restrict__ x, float* __restrict__ v, const float* __restrict__ iv,
    float* __restrict__ aggf, float* __restrict__ accf,
    const int* __restrict__ offs,
    const ushort_t* __restrict__ pn1, const ushort_t* __restrict__ pn2,
    const ushort_t* __restrict__ pv1,
    const float* __restrict__ nb1, const float* __restrict__ nb2,
    const float* __restrict__ vb1, const float* __restrict__ vb2,
    const float* __restrict__ vw2,
    float* __restrict__ outx, float* __restrict__ outv)
{
    __shared__ ushort_t t1[16*ALD];
    __shared__ float sPhi[16];

    const int lane = threadIdx.x;
    const int tile = blockIdx.x;
    const int quad = lane >> 4, lo = lane & 15;
    const int i0 = tile * 16;

    int ov = 0;
    if (lane < 17) ov = offs[i0 + lane];

    const ushort_t* hrow = hbf + (size_t)(i0 + lo) * HID;
    short8 af0 = *(const short8*)(hrow + quad*8);
    short8 af1 = *(const short8*)(hrow + 32 + quad*8);
    float* ag = aggf + (size_t)(i0 + lo) * HID + quad*8;
    short8 af2, af3;
    #pragma unroll
    for (int j = 0; j < 4; ++j) {
        const uint_t u2 = pk2bf(ag[2*j], ag[2*j+1]);
        const uint_t u3 = pk2bf(ag[32 + 2*j], ag[32 + 2*j+1]);
        af2[2*j] = (short)(u2 & 0xFFFFu); af2[2*j+1] = (short)(u2 >> 16);
        af3[2*j] = (short)(u3 & 0xFFFFu); af3[2*j+1] = (short)(u3 >> 16);
    }
    floatx4 z = {0.f, 0.f, 0.f, 0.f};
    *(floatx4*)(ag)      = z;
    *(floatx4*)(ag + 4)  = z;
    *(floatx4*)(ag + 32) = z;
    *(floatx4*)(ag + 36) = z;

    #pragma unroll
    for (int nt = 0; nt < 4; ++nt) {
        floatx4 a = {0.f, 0.f, 0.f, 0.f};
        a = __builtin_amdgcn_mfma_f32_16x16x32_bf16(af0, *(const short8*)(pn1 + ((size_t)(0*4+nt)*64+lane)*8), a, 0, 0, 0);
        a = __builtin_amdgcn_mfma_f32_16x16x32_bf16(af1, *(const short8*)(pn1 + ((size_t)(1*4+nt)*64+lane)*8), a, 0, 0, 0);
        a = __builtin_amdgcn_mfma_f32_16x16x32_bf16(af2, *(const short8*)(pn1 + ((size_t)(2*4+nt)*64+lane)*8), a, 0, 0, 0);
        a = __builtin_amdgcn_mfma_f32_16x16x32_bf16(af3, *(const short8*)(pn1 + ((size_t)(3*4+nt)*64+lane)*8), a, 0, 0, 0);
        const int n = 16*nt + lo;
        const float b1 = nb1[n];
        float vv[4];
        #pragma unroll
        for (int r = 0; r < 4; ++r) vv[r] = silu_f(a[r] + b1);
        const uint_t p01 = pk2bf(vv[0], vv[1]);
        const uint_t p23 = pk2bf(vv[2], vv[3]);
        t1[(4*quad + 0)*ALD + n] = (ushort_t)(p01 & 0xFFFFu);
        t1[(4*quad + 1)*ALD + n] = (ushort_t)(p01 >> 16);
        t1[(4*quad + 2)*ALD + n] = (ushort_t)(p23 & 0xFFFFu);
        t1[(4*quad + 3)*ALD + n] = (ushort_t)(p23 >> 16);
    }

    short8 g0 = *(const short8*)(t1 + lo*ALD + quad*8);
    short8 g1 = *(const short8*)(t1 + lo*ALD + 32 + quad*8);
    #pragma unroll
    for (int nt = 0; nt < 4; ++nt) {
        floatx4 a = {0.f, 0.f, 0.f, 0.f};
        a = __builtin_amdgcn_mfma_f32_16x16x32_bf16(g0, *(const short8*)(pn2 + ((size_t)(0*4+nt)*64+lane)*8), a, 0, 0, 0);
        a = __builtin_amdgcn_mfma_f32_16x16x32_bf16(g1, *(const short8*)(pn2 + ((size_t)(1*4+nt)*64+lane)*8), a, 0, 0, 0);
        const int n = 16*nt + lo;
        const float b2 = nb2[n];
        #pragma unroll
        for (int r = 0; r < 4; ++r) {
            const int i = i0 + 4*quad + r;
            const float hnew = h_in[(size_t)i*HID + n] + a[r] + b2;
            h_out[(size_t)i*HID + n] = hnew;
            hbf[(size_t)i*HID + n] = f2bf(hnew);
        }
    }

    float gs[4] = {0.f, 0.f, 0.f, 0.f};
    #pragma unroll
    for (int nt = 0; nt < 4; ++nt) {
        floatx4 a = {0.f, 0.f, 0.f, 0.f};
        a = __builtin_amdgcn_mfma_f32_16x16x32_bf16(af0, *(const short8*)(pv1 + ((size_t)(0*4+nt)*64+lane)*8), a, 0, 0, 0);
        a = __builtin_amdgcn_mfma_f32_16x16x32_bf16(af1, *(const short8*)(pv1 + ((size_t)(1*4+nt)*64+lane)*8), a, 0, 0, 0);
        const int n = 16*nt + lo;
        const float b1 = vb1[n], w2 = vw2[n];
        #pragma unroll
        for (int r = 0; r < 4; ++r) gs[r] += silu_f(a[r] + b1) * w2;
    }
    #pragma unroll
    for (int off = 1; off < 16; off <<= 1) {
        #pragma unroll
        for (int r = 0; r < 4; ++r) gs[r] += __shfl_xor(gs[r], off, 64);
    }
    const float vb2s = vb2[0];
    if (lo == 0) {
        #pragma unroll
        for (int r = 0; r < 4; ++r) sPhi[4*quad + r] = gs[r] + vb2s;
    }

    if (lane < 48) {
        const int m = lane / 3, d = lane - m*3;
        const int s = __shfl(ov, m, 64), t = __shfl(ov, m + 1, 64);
        const int cnt = t - s;
        const int i = i0 + m;
        const float accm = accf[(size_t)i*3 + d] / (float)(cnt > 0 ? cnt : 1);
        accf[(size_t)i*3 + d] = 0.f;
        const float phi = sPhi[m];
        const float vn = v[3*i + d] + accm + phi * iv[3*i + d];
        const float xn = x[3*i + d] + vn;
        v[3*i + d] = vn;
        x[3*i + d] = xn;
        if (outx) {
            outx[3*i + d] = xn;
            outv[3*i + d] = vn;
        }
    }
}

extern "C" void kernel_launch(void* const* d_in, const int* in_sizes, int n_in,
                              void* d_out, int out_size, void* d_ws, size_t ws_size,
                              hipStream_t stream) {
    const float* his   = (const float*)d_in[0];
    const float* loc   = (const float*)d_in[1];
    const int*   edges = (const int*)  d_in[2];
    const float* vel   = (const float*)d_in[3];
    const float* eattr = (const float*)d_in[4];
    const float* emb_w = (const float*)d_in[5];
    const float* emb_b = (const float*)d_in[6];
    const float* ew1 = (const float*)d_in[7];
    const float* eb1 = (const float*)d_in[8];
    const float* ew2 = (const float*)d_in[9];
    const float* eb2 = (const float*)d_in[10];
    const float* nw1 = (const float*)d_in[11];
    const float* nb1 = (const float*)d_in[12];
    const float* nw2 = (const float*)d_in[13];
    const float* nb2 = (const float*)d_in[14];
    const float* cw1 = (const float*)d_in[15];
    const float* cb1 = (const float*)d_in[16];
    const float* cw2 = (const float*)d_in[17];
    const float* vw1 = (const float*)d_in[18];
    const float* vb1 = (const float*)d_in[19];
    const float* vw2 = (const float*)d_in[20];
    const float* vb2 = (const float*)d_in[21];

    const int* erow = edges;
    const int* ecol = edges + N_EDGES;

    char* ws = (char*)d_ws;
    size_t off = 0;
    auto walloc = [&](size_t bytes) -> void* {
        void* p = ws + off; off += (bytes + 255) & ~(size_t)255; return p;
    };
    float* h_a      = (float*)walloc((size_t)N_NODES*HID*4);
    float* h_b      = (float*)walloc((size_t)N_NODES*HID*4);
    ushort_t* hbf   = (ushort_t*)walloc((size_t)N_NODES*HID*2);
    float* xb       = (float*)walloc((size_t)N_NODES*3*4);
    float* vb       = (float*)walloc((size_t)N_NODES*3*4);
    float* ivb      = (float*)walloc((size_t)N_NODES*3*4);
    float* aggf     = (float*)walloc((size_t)N_NODES*HID*4);
    float* accf     = (float*)walloc((size_t)N_NODES*3*4);
    int* counts     = (int*)walloc((size_t)N_NODES*4);
    int* cursor     = (int*)walloc((size_t)N_NODES*4);
    int* offs       = (int*)walloc((size_t)(N_NODES+1)*4);
    int* srow       = (int*)walloc((size_t)N_EDGES*4);
    int* scol       = (int*)walloc((size_t)N_EDGES*4);
    float* seattr   = (float*)walloc((size_t)N_EDGES*2*4);
    ushort_t* pw1   = (ushort_t*)walloc((size_t)4*4*64*8*2);
    ushort_t* pw2   = (ushort_t*)walloc((size_t)2*4*64*8*2);
    ushort_t* pc1   = (ushort_t*)walloc((size_t)2*4*64*8*2);
    ushort_t* pn1   = (ushort_t*)walloc((size_t)4*4*64*8*2);
    ushort_t* pn2   = (ushort_t*)walloc((size_t)2*4*64*8*2);
    ushort_t* pv1   = (ushort_t*)walloc((size_t)2*4*64*8*2);

    float* out = (float*)d_out;
    const int nx = 3*N_NODES, nh = HID*N_NODES;

    (void)hipMemsetAsync(counts, 0, (size_t)N_NODES*4, stream);
    (void)hipMemsetAsync(cursor, 0, (size_t)N_NODES*4, stream);
    (void)hipMemsetAsync(aggf, 0, (size_t)N_NODES*HID*4, stream);
    (void)hipMemsetAsync(accf, 0, (size_t)N_NODES*3*4, stream);

    embed_kernel<<<N_NODES, 64, 0, stream>>>(his, loc, vel, emb_w, emb_b, h_a, hbf,
                                             xb, vb, ivb);
    count_kernel<<<(N_EDGES+255)/256, 256, 0, stream>>>(erow, counts);
    scan_kernel<<<1, 256, 0, stream>>>(counts, offs);
    scatter_kernel<<<(N_EDGES+255)/256, 256, 0, stream>>>(erow, ecol, eattr, offs, cursor,
                                                          srow, scol, seattr);
    pack_weights<<<16, 256, 0, stream>>>(ew1, ew2, cw1, nw1, nw2, vw1,
                                         pw1, pw2, pc1, pn1, pn2, pv1);

    float* h_cur = h_a;
    float* h_nxt = h_b;
    for (int layer = 0; layer < N_LAYERS; ++layer) {
        const bool last = (layer == N_LAYERS - 1);
        edge_kernel<<<EDGE_BLOCKS, 256, 0, stream>>>(hbf, xb, srow, scol, seattr,
                                                     ew1, eb1, eb2, cb1, cw2,
                                                     pw1, pw2, pc1, aggf, accf);
        node_kernel<<<N_TILES_NODE, 64, 0, stream>>>(h_cur,
                                                     last ? (out + nx) : h_nxt,
                                                     hbf, xb, vb, ivb,
                                                     aggf, accf, offs,
                                                     pn1, pn2, pv1,
                                                     nb1, nb2, vb1, vb2, vw2,
                                                     last ? out : nullptr,
                                                     last ? (out + nx + nh) : nullptr);
        float* tmp = h_cur; h_cur = h_nxt; h_nxt = tmp;
    }
}